// Round 2
// baseline (17219.757 us; speedup 1.0000x reference)
//
#include <hip/hip_runtime.h>
#include <hip/hip_bf16.h>

// Model dims
#define BN 64      // batch
#define TT 192     // total seq
#define ILEN 160   // input_len
#define DIN 8
#define DM 256
#define NH 8
#define DH 32
#define DFF 1024
#define NLAY 4
#define PRE_ROWS (BN * ILEN)   // 10240
#define SCALE 0.17677669529663687f  // 1/sqrt(32)

typedef _Float16 h2_t __attribute__((ext_vector_type(2)));

#if defined(__has_builtin)
#if __has_builtin(__builtin_amdgcn_fdot2)
#define FDOT2(a, b, c) __builtin_amdgcn_fdot2((a), (b), (c), false)
#endif
#endif
#ifndef FDOT2
static __device__ inline float fdot2_fb(h2_t a, h2_t b, float c) {
    return c + (float)a.x * (float)b.x + (float)a.y * (float)b.y;
}
#define FDOT2(a, b, c) fdot2_fb((a), (b), (c))
#endif

// ---------------- copy whole_example -> out ----------------
__global__ void copy_out_k(const float* __restrict__ X, float* __restrict__ O, int n) {
    int i = blockIdx.x * blockDim.x + threadIdx.x;
    if (i < n) O[i] = X[i];
}

// ---------------- pack fp32 [2*Rp][N] -> half2 [Rp][N] (pairs along rows) ----------------
__global__ __launch_bounds__(256) void pack_k(const float* __restrict__ src,
        h2_t* __restrict__ dst, int N) {
    int o = blockIdx.x * 256 + threadIdx.x;
    int rp = blockIdx.y;
    if (o < N) {
        h2_t v;
        v.x = (_Float16)src[(size_t)(2 * rp) * N + o];
        v.y = (_Float16)src[(size_t)(2 * rp + 1) * N + o];
        dst[(size_t)rp * N + o] = v;
    }
}

// ---------------- embedding for prefill rows ----------------
__global__ __launch_bounds__(256) void embed_k(const float* __restrict__ X,
        const float* __restrict__ w, const float* __restrict__ bias,
        float* __restrict__ H) {
    int row = blockIdx.x;            // b*160 + p
    int b = row / ILEN, p = row % ILEN;
    int tid = threadIdx.x;
    const float* x = X + (size_t)(b * TT + p) * DIN;
    float acc = bias[tid];
#pragma unroll
    for (int r = 0; r < DIN; ++r) acc += x[r] * w[r * DM + tid];
    H[(size_t)row * DM + tid] = acc;
}

// ---------------- generic fp32 tiled GEMM: C = A@W + bias (+epilogue) ----------------
__global__ __launch_bounds__(256) void gemm_k(
        const float* __restrict__ A, const float* __restrict__ W,
        const float* __restrict__ bias, const float* __restrict__ R,
        float* __restrict__ C, int M, int N, int K, int mode, int remap) {
    __shared__ float As[16][64];
    __shared__ float Bs[16][64];
    int tid = threadIdx.x;
    int bx = blockIdx.x, by = blockIdx.y;
    int tx = tid & 15, ty = tid >> 4;
    int row0 = by * 64 + ty * 4;
    int col0 = bx * 64 + tx * 4;
    float acc[4][4] = {};
    int arow = tid >> 2, ak4 = tid & 3;
    int brow = tid >> 4, bc4 = tid & 15;
    const float* aptr = A + (size_t)(by * 64 + arow) * K + ak4 * 4;
    const float* bptr = W + (size_t)brow * N + bx * 64 + bc4 * 4;
    for (int kt = 0; kt < K; kt += 16) {
        float4 av = *(const float4*)(aptr + kt);
        float4 bv = *(const float4*)(bptr + (size_t)kt * N);
        As[ak4 * 4 + 0][arow] = av.x;
        As[ak4 * 4 + 1][arow] = av.y;
        As[ak4 * 4 + 2][arow] = av.z;
        As[ak4 * 4 + 3][arow] = av.w;
        *(float4*)&Bs[brow][bc4 * 4] = bv;
        __syncthreads();
#pragma unroll
        for (int k = 0; k < 16; ++k) {
            float a[4], bb[4];
#pragma unroll
            for (int i = 0; i < 4; ++i) a[i] = As[k][ty * 4 + i];
#pragma unroll
            for (int j = 0; j < 4; ++j) bb[j] = Bs[k][tx * 4 + j];
#pragma unroll
            for (int i = 0; i < 4; ++i)
#pragma unroll
                for (int j = 0; j < 4; ++j) acc[i][j] += a[i] * bb[j];
        }
        __syncthreads();
    }
#pragma unroll
    for (int i = 0; i < 4; ++i) {
        int row = row0 + i;
        int orow = remap ? (row / ILEN) * TT + (row % ILEN) : row;
#pragma unroll
        for (int j = 0; j < 4; ++j) {
            int col = col0 + j;
            float v = acc[i][j] + bias[col];
            if (mode == 1) v = fmaxf(v, 0.f);
            if (mode == 2) v += R[(size_t)row * N + col];
            C[(size_t)orow * N + col] = v;
        }
    }
}

// ---------------- prefill attention: one block per (q position, batch) ----------------
__global__ __launch_bounds__(256) void attn_k(
        const float* __restrict__ Q, const float* __restrict__ Kc,
        const float* __restrict__ Vc, float* __restrict__ O) {
    int qp = blockIdx.x;    // 0..159
    int b = blockIdx.y;
    int tid = threadIdx.x;
    int hh = tid >> 5, l = tid & 31;
    __shared__ float qs[DM];
    __shared__ float sc[NH][TT];
    int qrow = b * ILEN + qp;
    qs[tid] = Q[(size_t)qrow * DM + tid] * SCALE;
    __syncthreads();
    const float* Kb = Kc + (size_t)b * TT * DM;
    const float* Vb = Vc + (size_t)b * TT * DM;
    float mx = -1e30f;
    for (int j = l; j <= qp; j += 32) {
        const float* kr = Kb + (size_t)j * DM + hh * DH;
        float d = 0.f;
#pragma unroll
        for (int u = 0; u < DH; ++u) d += qs[hh * DH + u] * kr[u];
        sc[hh][j] = d;
        mx = fmaxf(mx, d);
    }
#pragma unroll
    for (int o = 16; o > 0; o >>= 1) mx = fmaxf(mx, __shfl_xor(mx, o, 32));
    float sum = 0.f;
    for (int j = l; j <= qp; j += 32) {
        float p = __expf(sc[hh][j] - mx);
        sc[hh][j] = p;
        sum += p;
    }
#pragma unroll
    for (int o = 16; o > 0; o >>= 1) sum += __shfl_xor(sum, o, 32);
    float inv = 1.f / sum;
    float acc = 0.f;
    for (int j = 0; j <= qp; ++j)
        acc += sc[hh][j] * Vb[(size_t)j * DM + hh * DH + l];
    O[(size_t)qrow * DM + hh * DH + l] = acc * inv;
}

// ---------------- layernorm over rows of 256 ----------------
__global__ __launch_bounds__(256) void ln_k(const float* __restrict__ Xp,
        const float* __restrict__ g, const float* __restrict__ be,
        float* __restrict__ Y) {
    int row = blockIdx.x;
    int tid = threadIdx.x;
    float x = Xp[(size_t)row * DM + tid];
    float s = x, s2 = x * x;
#pragma unroll
    for (int o = 32; o > 0; o >>= 1) { s += __shfl_xor(s, o); s2 += __shfl_xor(s2, o); }
    __shared__ float red[8];
    if ((tid & 63) == 0) { red[tid >> 6] = s; red[4 + (tid >> 6)] = s2; }
    __syncthreads();
    s = red[0] + red[1] + red[2] + red[3];
    s2 = red[4] + red[5] + red[6] + red[7];
    float m = s * (1.f / 256.f);
    float var = s2 * (1.f / 256.f) - m * m;
    float r = rsqrtf(var + 1e-5f);
    Y[(size_t)row * DM + tid] = (x - m) * r * g[tid] + be[tid];
}

// ---------------- final projection at position 159 -> pred0 ----------------
__global__ __launch_bounds__(256) void final_k(const float* __restrict__ H,
        const float* __restrict__ fw, const float* __restrict__ fb,
        float* __restrict__ out) {
    int b = blockIdx.x;
    int tid = threadIdx.x;
    float v = H[(size_t)(b * ILEN + ILEN - 1) * DM + tid] * fw[tid];
#pragma unroll
    for (int o = 32; o > 0; o >>= 1) v += __shfl_xor(v, o);
    __shared__ float red[4];
    if ((tid & 63) == 0) red[tid >> 6] = v;
    __syncthreads();
    if (tid == 0)
        out[((size_t)b * TT + ILEN) * DIN] = red[0] + red[1] + red[2] + red[3] + fb[0];
}

// ---------------- persistent decode v2: 1024 threads/block, f16 weights ----------------
__global__ __launch_bounds__(1024) void decode2_k(
        const float* __restrict__ X,
        const float* __restrict__ emb_w, const float* __restrict__ emb_b,
        const float* __restrict__ bq, const float* __restrict__ bk,
        const float* __restrict__ bv, const float* __restrict__ bo,
        const float* __restrict__ ln1g, const float* __restrict__ ln1b,
        const float* __restrict__ b1, const float* __restrict__ b2,
        const float* __restrict__ ln2g, const float* __restrict__ ln2b,
        const float* __restrict__ fw, const float* __restrict__ fb,
        const h2_t* __restrict__ embp, const h2_t* __restrict__ qp,
        const h2_t* __restrict__ kp, const h2_t* __restrict__ vp,
        const h2_t* __restrict__ op, const h2_t* __restrict__ w1p,
        const h2_t* __restrict__ w2p,
        float* __restrict__ Kc, float* __restrict__ Vc,
        float* __restrict__ out) {
    int b = blockIdx.x;
    int tid = threadIdx.x;
    int wid = tid >> 6;                 // wave 0..15
    int hh8 = tid >> 7;                 // head 0..7 (attn)
    int sub = tid & 127;
    int l = sub & 31;                   // dim within head
    int cw = sub >> 5;                  // 0..3 chunk within head
    int c = tid >> 8;                   // 0..3 reduction chunk (GEMV)
    int o = tid & 255;                  // output dim (GEMV)

    __shared__ float hs[256], qs[256], pre[256], ffs[1024];
    __shared__ h2_t h2[128], ff2[512], as2[128];
    __shared__ float sc[8][192];
    __shared__ float pA[4][256], pB[4][256], pC[4][256];
    __shared__ float red[16], red2[16], hinv[8];
    __shared__ float xs[8];
    __shared__ float pred_s;

    if (tid == 0) pred_s = out[((size_t)b * TT + ILEN) * DIN];

    for (int t = 0; t < TT - ILEN - 1; ++t) {   // 31 steps
        int p = ILEN + t;
        __syncthreads();
        if (tid < 8) xs[tid] = (tid == 0) ? pred_s : X[((size_t)b * TT + p) * DIN + tid];
        __syncthreads();
        if (tid < 256) {
            float h0 = emb_b[tid];
#pragma unroll
            for (int r = 0; r < DIN; ++r) h0 += xs[r] * emb_w[r * DM + tid];
            hs[tid] = h0;
        }
        __syncthreads();
        if (tid < 128) {
            h2_t v; v.x = (_Float16)hs[2 * tid]; v.y = (_Float16)hs[2 * tid + 1];
            h2[tid] = v;
        }
        __syncthreads();

        for (int li = 0; li < NLAY; ++li) {
            const h2_t* wq2 = qp + (size_t)li * 32768;
            const h2_t* wk2 = kp + (size_t)li * 32768;
            const h2_t* wv2 = vp + (size_t)li * 32768;
            const h2_t* wo2 = op + (size_t)li * 32768;
            const h2_t* w12 = w1p + (size_t)li * 131072;
            const h2_t* w22 = w2p + (size_t)li * 131072;
            float* Kb = Kc + (size_t)(li * BN + b) * TT * DM;
            float* Vb = Vc + (size_t)(li * BN + b) * TT * DM;

            // ---- QKV: thread (c,o), reduction chunk c of 32 half2-pairs ----
            {
                float aq = 0.f, ak = 0.f, av = 0.f;
                int base = c * 32;
#pragma unroll 8
                for (int i = 0; i < 32; ++i) {
                    int rp = base + i;
                    h2_t hv = h2[rp];
                    aq = FDOT2(hv, wq2[rp * 256 + o], aq);
                    ak = FDOT2(hv, wk2[rp * 256 + o], ak);
                    av = FDOT2(hv, wv2[rp * 256 + o], av);
                }
                pA[c][o] = aq; pB[c][o] = ak; pC[c][o] = av;
            }
            __syncthreads();
            if (tid < 256) {
                float q = (bq[li * DM + tid] + pA[0][tid] + pA[1][tid] + pA[2][tid] + pA[3][tid]) * SCALE;
                float k = bk[li * DM + tid] + pB[0][tid] + pB[1][tid] + pB[2][tid] + pB[3][tid];
                float v = bv[li * DM + tid] + pC[0][tid] + pC[1][tid] + pC[2][tid] + pC[3][tid];
                qs[tid] = q;
                Kb[(size_t)p * DM + tid] = k;
                Vb[(size_t)p * DM + tid] = v;
            }
            __syncthreads();

            // ---- attention: 128 threads/head (2 waves) ----
            float mx = -1e30f;
            for (int j = cw * 32 + l; j <= p; j += 128) {
                const float* kr = Kb + (size_t)j * DM + hh8 * DH;
                float d = 0.f;
#pragma unroll
                for (int u = 0; u < DH; ++u) d += qs[hh8 * DH + u] * kr[u];
                sc[hh8][j] = d;
                mx = fmaxf(mx, d);
            }
#pragma unroll
            for (int s = 32; s > 0; s >>= 1) mx = fmaxf(mx, __shfl_xor(mx, s));
            if ((tid & 63) == 0) red[wid] = mx;
            __syncthreads();
            mx = fmaxf(red[wid & ~1], red[wid | 1]);
            float sum = 0.f;
            for (int j = cw * 32 + l; j <= p; j += 128) {
                float pe = __expf(sc[hh8][j] - mx);
                sc[hh8][j] = pe;
                sum += pe;
            }
#pragma unroll
            for (int s = 32; s > 0; s >>= 1) sum += __shfl_xor(sum, s);
            if ((tid & 63) == 0) red2[wid] = sum;
            __syncthreads();
            if (sub == 0) hinv[hh8] = 1.f / (red2[wid & ~1] + red2[wid | 1]);
            // PV: thread (hh8, cw, l): output dim l, j-chunk cw
            float acc = 0.f;
            for (int j = cw; j <= p; j += 4)
                acc += sc[hh8][j] * Vb[(size_t)j * DM + hh8 * DH + l];
            pA[cw][hh8 * DH + l] = acc;
            __syncthreads();
            if (tid < 256)
                qs[tid] = (pA[0][tid] + pA[1][tid] + pA[2][tid] + pA[3][tid]) * hinv[tid >> 5];
            __syncthreads();
            if (tid < 128) {
                h2_t v; v.x = (_Float16)qs[2 * tid]; v.y = (_Float16)qs[2 * tid + 1];
                as2[tid] = v;
            }
            __syncthreads();

            // ---- O-projection ----
            {
                float ao = 0.f;
                int base = c * 32;
#pragma unroll 8
                for (int i = 0; i < 32; ++i) {
                    int rp = base + i;
                    ao = FDOT2(as2[rp], wo2[rp * 256 + o], ao);
                }
                pB[c][o] = ao;
            }
            __syncthreads();
            if (tid < 256)
                pre[tid] = bo[li * DM + tid] + hs[tid] + pB[0][tid] + pB[1][tid] + pB[2][tid] + pB[3][tid];
            __syncthreads();
            // ---- LN1 ----
            {
                float x = (tid < 256) ? pre[tid] : 0.f;
                float s = x, s2 = x * x;
#pragma unroll
                for (int ss = 32; ss > 0; ss >>= 1) { s += __shfl_xor(s, ss); s2 += __shfl_xor(s2, ss); }
                if (tid < 256 && (tid & 63) == 0) { red[wid] = s; red2[wid] = s2; }
                __syncthreads();
                if (tid < 256) {
                    float S = red[0] + red[1] + red[2] + red[3];
                    float S2 = red2[0] + red2[1] + red2[2] + red2[3];
                    float m = S * (1.f / 256.f);
                    float var = S2 * (1.f / 256.f) - m * m;
                    float r = rsqrtf(var + 1e-5f);
                    hs[tid] = (pre[tid] - m) * r * ln1g[li * DM + tid] + ln1b[li * DM + tid];
                }
                __syncthreads();
                if (tid < 128) {
                    h2_t v; v.x = (_Float16)hs[2 * tid]; v.y = (_Float16)hs[2 * tid + 1];
                    h2[tid] = v;
                }
                __syncthreads();
            }
            // ---- FFN1 (+relu): thread = one of 1024 outputs ----
            {
                float a = b1[li * DFF + tid];
#pragma unroll 8
                for (int rp = 0; rp < 128; ++rp)
                    a = FDOT2(h2[rp], w12[rp * 1024 + tid], a);
                ffs[tid] = fmaxf(a, 0.f);
            }
            __syncthreads();
            if (tid < 512) {
                h2_t v; v.x = (_Float16)ffs[2 * tid]; v.y = (_Float16)ffs[2 * tid + 1];
                ff2[tid] = v;
            }
            __syncthreads();
            // ---- FFN2: thread (c,o), chunk c of 128 half2-pairs ----
            {
                float a = 0.f;
                int base = c * 128;
#pragma unroll 8
                for (int i = 0; i < 128; ++i) {
                    int rp = base + i;
                    a = FDOT2(ff2[rp], w22[rp * 256 + o], a);
                }
                pC[c][o] = a;
            }
            __syncthreads();
            if (tid < 256)
                pre[tid] = b2[li * DM + tid] + hs[tid] + pC[0][tid] + pC[1][tid] + pC[2][tid] + pC[3][tid];
            __syncthreads();
            // ---- LN2 ----
            {
                float x = (tid < 256) ? pre[tid] : 0.f;
                float s = x, s2 = x * x;
#pragma unroll
                for (int ss = 32; ss > 0; ss >>= 1) { s += __shfl_xor(s, ss); s2 += __shfl_xor(s2, ss); }
                if (tid < 256 && (tid & 63) == 0) { red[wid] = s; red2[wid] = s2; }
                __syncthreads();
                if (tid < 256) {
                    float S = red[0] + red[1] + red[2] + red[3];
                    float S2 = red2[0] + red2[1] + red2[2] + red2[3];
                    float m = S * (1.f / 256.f);
                    float var = S2 * (1.f / 256.f) - m * m;
                    float r = rsqrtf(var + 1e-5f);
                    hs[tid] = (pre[tid] - m) * r * ln2g[li * DM + tid] + ln2b[li * DM + tid];
                }
                __syncthreads();
                if (tid < 128) {
                    h2_t v; v.x = (_Float16)hs[2 * tid]; v.y = (_Float16)hs[2 * tid + 1];
                    h2[tid] = v;
                }
                __syncthreads();
            }
        }
        // ---- final projection -> next pred ----
        {
            float v = (tid < 256) ? hs[tid] * fw[tid] : 0.f;
#pragma unroll
            for (int ss = 32; ss > 0; ss >>= 1) v += __shfl_xor(v, ss);
            if (tid < 256 && (tid & 63) == 0) red[wid] = v;
            __syncthreads();
            if (tid == 0) {
                float y = red[0] + red[1] + red[2] + red[3] + fb[0];
                out[((size_t)b * TT + p + 1) * DIN] = y;
                pred_s = y;
            }
        }
    }
}

extern "C" void kernel_launch(void* const* d_in, const int* in_sizes, int n_in,
                              void* d_out, int out_size, void* d_ws, size_t ws_size,
                              hipStream_t stream) {
    const float* X     = (const float*)d_in[0];
    const float* emb_w = (const float*)d_in[1];
    const float* emb_b = (const float*)d_in[2];
    const float* Wq    = (const float*)d_in[3];
    const float* bq    = (const float*)d_in[4];
    const float* Wk    = (const float*)d_in[5];
    const float* bk    = (const float*)d_in[6];
    const float* Wv    = (const float*)d_in[7];
    const float* bv    = (const float*)d_in[8];
    const float* Wo    = (const float*)d_in[9];
    const float* bo    = (const float*)d_in[10];
    const float* ln1g  = (const float*)d_in[11];
    const float* ln1b  = (const float*)d_in[12];
    const float* W1    = (const float*)d_in[13];
    const float* b1    = (const float*)d_in[14];
    const float* W2    = (const float*)d_in[15];
    const float* b2    = (const float*)d_in[16];
    const float* ln2g  = (const float*)d_in[17];
    const float* ln2b  = (const float*)d_in[18];
    const float* fw    = (const float*)d_in[19];
    const float* fb    = (const float*)d_in[20];
    float* out = (float*)d_out;

    // workspace layout (floats)
    float* ws = (float*)d_ws;
    const size_t HROWS = (size_t)PRE_ROWS * DM;        // 2,621,440
    float* h   = ws;
    float* qa  = ws + HROWS;
    float* pre = ws + 2 * HROWS;
    float* ff  = ws + 3 * HROWS;
    float* Kc  = ws + 3 * HROWS + (size_t)PRE_ROWS * DFF;
    float* Vc  = Kc + (size_t)NLAY * BN * TT * DM;
    const size_t LSL = (size_t)BN * TT * DM;           // per-layer cache slice
    // packed f16 weights after Vc
    float* pk_base = Vc + (size_t)NLAY * BN * TT * DM;
    h2_t* embp = (h2_t*)pk_base;                       // 4 x 256
    h2_t* qp   = embp + 1024;                          // 4 layers x 128 x 256
    h2_t* kp   = qp + 131072;
    h2_t* vp   = kp + 131072;
    h2_t* op   = vp + 131072;
    h2_t* w1p  = op + 131072;                          // 4 layers x 128 x 1024
    h2_t* w2p  = w1p + 524288;                         // 4 layers x 512 x 256

    // pack weights to half2 (pairs along reduction dim)
    pack_k<<<dim3(1, 4),    256, 0, stream>>>(emb_w, embp, DM);
    pack_k<<<dim3(1, 512),  256, 0, stream>>>(Wq, qp, DM);
    pack_k<<<dim3(1, 512),  256, 0, stream>>>(Wk, kp, DM);
    pack_k<<<dim3(1, 512),  256, 0, stream>>>(Wv, vp, DM);
    pack_k<<<dim3(1, 512),  256, 0, stream>>>(Wo, op, DM);
    pack_k<<<dim3(4, 512),  256, 0, stream>>>(W1, w1p, DFF);
    pack_k<<<dim3(1, 2048), 256, 0, stream>>>(W2, w2p, DM);

    copy_out_k<<<(BN * TT * DIN + 255) / 256, 256, 0, stream>>>(X, out, BN * TT * DIN);
    embed_k<<<PRE_ROWS, 256, 0, stream>>>(X, emb_w, emb_b, h);

    for (int li = 0; li < NLAY; ++li) {
        const float* wq = Wq + (size_t)li * DM * DM;
        const float* wk = Wk + (size_t)li * DM * DM;
        const float* wv = Wv + (size_t)li * DM * DM;
        const float* wo = Wo + (size_t)li * DM * DM;
        const float* w1 = W1 + (size_t)li * DM * DFF;
        const float* w2 = W2 + (size_t)li * DFF * DM;
        gemm_k<<<dim3(4, 160), 256, 0, stream>>>(h, wq, bq + li * DM, nullptr, qa,
                                                 PRE_ROWS, DM, DM, 0, 0);
        gemm_k<<<dim3(4, 160), 256, 0, stream>>>(h, wk, bk + li * DM, nullptr, Kc + li * LSL,
                                                 PRE_ROWS, DM, DM, 0, 1);
        gemm_k<<<dim3(4, 160), 256, 0, stream>>>(h, wv, bv + li * DM, nullptr, Vc + li * LSL,
                                                 PRE_ROWS, DM, DM, 0, 1);
        attn_k<<<dim3(ILEN, BN), 256, 0, stream>>>(qa, Kc + li * LSL, Vc + li * LSL, qa);
        gemm_k<<<dim3(4, 160), 256, 0, stream>>>(qa, wo, bo + li * DM, h, pre,
                                                 PRE_ROWS, DM, DM, 2, 0);
        ln_k<<<PRE_ROWS, 256, 0, stream>>>(pre, ln1g + li * DM, ln1b + li * DM, h);
        gemm_k<<<dim3(16, 160), 256, 0, stream>>>(h, w1, b1 + li * DFF, nullptr, ff,
                                                  PRE_ROWS, DFF, DM, 1, 0);
        gemm_k<<<dim3(4, 160), 256, 0, stream>>>(ff, w2, b2 + li * DM, h, pre,
                                                 PRE_ROWS, DM, DFF, 2, 0);
        ln_k<<<PRE_ROWS, 256, 0, stream>>>(pre, ln2g + li * DM, ln2b + li * DM, h);
    }
    final_k<<<BN, 256, 0, stream>>>(h, fw, fb, out);

    decode2_k<<<BN, 1024, 0, stream>>>(X, emb_w, emb_b, bq, bk, bv, bo,
                                       ln1g, ln1b, b1, b2, ln2g, ln2b, fw, fb,
                                       embp, qp, kp, vp, op, w1p, w2p,
                                       Kc, Vc, out);
}

// Round 3
// 9550.144 us; speedup vs baseline: 1.8031x; 1.8031x over previous
//
#include <hip/hip_runtime.h>
#include <hip/hip_bf16.h>

// Model dims
#define BN 64      // batch
#define TT 192     // total seq
#define ILEN 160   // input_len
#define DIN 8
#define DM 256
#define NH 8
#define DH 32
#define DFF 1024
#define NLAY 4
#define PRE_ROWS (BN * ILEN)   // 10240
#define SCALE 0.17677669529663687f  // 1/sqrt(32)
#define GROUP 4                // decode blocks per batch

typedef _Float16 h2_t __attribute__((ext_vector_type(2)));

#if defined(__has_builtin)
#if __has_builtin(__builtin_amdgcn_fdot2)
#define FDOT2(a, b, c) __builtin_amdgcn_fdot2((a), (b), (c), false)
#endif
#endif
#ifndef FDOT2
static __device__ inline float fdot2_fb(h2_t a, h2_t b, float c) {
    return c + (float)a.x * (float)b.x + (float)a.y * (float)b.y;
}
#define FDOT2(a, b, c) fdot2_fb((a), (b), (c))
#endif

// ---------------- copy whole_example -> out ----------------
__global__ void copy_out_k(const float* __restrict__ X, float* __restrict__ O, int n) {
    int i = blockIdx.x * blockDim.x + threadIdx.x;
    if (i < n) O[i] = X[i];
}

// ---------------- zero the group-barrier counters ----------------
__global__ void init_ctr_k(unsigned* __restrict__ ctr) {
    if (threadIdx.x < BN) ctr[threadIdx.x] = 0u;
}

// ---------------- pack fp32 [2*Rp][N] -> half2 [Rp][N] ----------------
__global__ __launch_bounds__(256) void pack_k(const float* __restrict__ src,
        h2_t* __restrict__ dst, int N) {
    int o = blockIdx.x * 256 + threadIdx.x;
    int rp = blockIdx.y;
    if (o < N) {
        h2_t v;
        v.x = (_Float16)src[(size_t)(2 * rp) * N + o];
        v.y = (_Float16)src[(size_t)(2 * rp + 1) * N + o];
        dst[(size_t)rp * N + o] = v;
    }
}

// ---------------- convert prefill fp32 KV (rows 0..159) -> f16 pairs ----------------
__global__ __launch_bounds__(256) void kvconv_k(const float* __restrict__ Kc,
        const float* __restrict__ Vc, h2_t* __restrict__ K16, h2_t* __restrict__ V16) {
    size_t i = (size_t)blockIdx.x * 256 + threadIdx.x;   // over 256 lb * 160 j * 128 pi
    int pi = i & 127;
    size_t r = i >> 7;
    int j = (int)(r % ILEN);
    size_t lb = r / ILEN;
    size_t src = (lb * TT + j) * DM + 2 * pi;
    size_t dst = (lb * TT + j) * (DM / 2) + pi;
    h2_t k, v;
    k.x = (_Float16)Kc[src]; k.y = (_Float16)Kc[src + 1];
    v.x = (_Float16)Vc[src]; v.y = (_Float16)Vc[src + 1];
    K16[dst] = k;
    V16[dst] = v;
}

// ---------------- embedding for prefill rows ----------------
__global__ __launch_bounds__(256) void embed_k(const float* __restrict__ X,
        const float* __restrict__ w, const float* __restrict__ bias,
        float* __restrict__ H) {
    int row = blockIdx.x;
    int b = row / ILEN, p = row % ILEN;
    int tid = threadIdx.x;
    const float* x = X + (size_t)(b * TT + p) * DIN;
    float acc = bias[tid];
#pragma unroll
    for (int r = 0; r < DIN; ++r) acc += x[r] * w[r * DM + tid];
    H[(size_t)row * DM + tid] = acc;
}

// ---------------- generic fp32 tiled GEMM (prefill) ----------------
__global__ __launch_bounds__(256) void gemm_k(
        const float* __restrict__ A, const float* __restrict__ W,
        const float* __restrict__ bias, const float* __restrict__ R,
        float* __restrict__ C, int M, int N, int K, int mode, int remap) {
    __shared__ float As[16][64];
    __shared__ float Bs[16][64];
    int tid = threadIdx.x;
    int bx = blockIdx.x, by = blockIdx.y;
    int tx = tid & 15, ty = tid >> 4;
    int row0 = by * 64 + ty * 4;
    int col0 = bx * 64 + tx * 4;
    float acc[4][4] = {};
    int arow = tid >> 2, ak4 = tid & 3;
    int brow = tid >> 4, bc4 = tid & 15;
    const float* aptr = A + (size_t)(by * 64 + arow) * K + ak4 * 4;
    const float* bptr = W + (size_t)brow * N + bx * 64 + bc4 * 4;
    for (int kt = 0; kt < K; kt += 16) {
        float4 av = *(const float4*)(aptr + kt);
        float4 bv = *(const float4*)(bptr + (size_t)kt * N);
        As[ak4 * 4 + 0][arow] = av.x;
        As[ak4 * 4 + 1][arow] = av.y;
        As[ak4 * 4 + 2][arow] = av.z;
        As[ak4 * 4 + 3][arow] = av.w;
        *(float4*)&Bs[brow][bc4 * 4] = bv;
        __syncthreads();
#pragma unroll
        for (int k = 0; k < 16; ++k) {
            float a[4], bb[4];
#pragma unroll
            for (int i = 0; i < 4; ++i) a[i] = As[k][ty * 4 + i];
#pragma unroll
            for (int j = 0; j < 4; ++j) bb[j] = Bs[k][tx * 4 + j];
#pragma unroll
            for (int i = 0; i < 4; ++i)
#pragma unroll
                for (int j = 0; j < 4; ++j) acc[i][j] += a[i] * bb[j];
        }
        __syncthreads();
    }
#pragma unroll
    for (int i = 0; i < 4; ++i) {
        int row = row0 + i;
        int orow = remap ? (row / ILEN) * TT + (row % ILEN) : row;
#pragma unroll
        for (int j = 0; j < 4; ++j) {
            int col = col0 + j;
            float v = acc[i][j] + bias[col];
            if (mode == 1) v = fmaxf(v, 0.f);
            if (mode == 2) v += R[(size_t)row * N + col];
            C[(size_t)orow * N + col] = v;
        }
    }
}

// ---------------- prefill attention ----------------
__global__ __launch_bounds__(256) void attn_k(
        const float* __restrict__ Q, const float* __restrict__ Kc,
        const float* __restrict__ Vc, float* __restrict__ O) {
    int qp = blockIdx.x;
    int b = blockIdx.y;
    int tid = threadIdx.x;
    int hh = tid >> 5, l = tid & 31;
    __shared__ float qs[DM];
    __shared__ float sc[NH][TT];
    int qrow = b * ILEN + qp;
    qs[tid] = Q[(size_t)qrow * DM + tid] * SCALE;
    __syncthreads();
    const float* Kb = Kc + (size_t)b * TT * DM;
    const float* Vb = Vc + (size_t)b * TT * DM;
    float mx = -1e30f;
    for (int j = l; j <= qp; j += 32) {
        const float* kr = Kb + (size_t)j * DM + hh * DH;
        float d = 0.f;
#pragma unroll
        for (int u = 0; u < DH; ++u) d += qs[hh * DH + u] * kr[u];
        sc[hh][j] = d;
        mx = fmaxf(mx, d);
    }
#pragma unroll
    for (int o = 16; o > 0; o >>= 1) mx = fmaxf(mx, __shfl_xor(mx, o, 32));
    float sum = 0.f;
    for (int j = l; j <= qp; j += 32) {
        float p = __expf(sc[hh][j] - mx);
        sc[hh][j] = p;
        sum += p;
    }
#pragma unroll
    for (int o = 16; o > 0; o >>= 1) sum += __shfl_xor(sum, o, 32);
    float inv = 1.f / sum;
    float acc = 0.f;
    for (int j = 0; j <= qp; ++j)
        acc += sc[hh][j] * Vb[(size_t)j * DM + hh * DH + l];
    O[(size_t)qrow * DM + hh * DH + l] = acc * inv;
}

// ---------------- layernorm over rows of 256 (prefill) ----------------
__global__ __launch_bounds__(256) void ln_k(const float* __restrict__ Xp,
        const float* __restrict__ g, const float* __restrict__ be,
        float* __restrict__ Y) {
    int row = blockIdx.x;
    int tid = threadIdx.x;
    float x = Xp[(size_t)row * DM + tid];
    float s = x, s2 = x * x;
#pragma unroll
    for (int o = 32; o > 0; o >>= 1) { s += __shfl_xor(s, o); s2 += __shfl_xor(s2, o); }
    __shared__ float red[8];
    if ((tid & 63) == 0) { red[tid >> 6] = s; red[4 + (tid >> 6)] = s2; }
    __syncthreads();
    s = red[0] + red[1] + red[2] + red[3];
    s2 = red[4] + red[5] + red[6] + red[7];
    float m = s * (1.f / 256.f);
    float var = s2 * (1.f / 256.f) - m * m;
    float r = rsqrtf(var + 1e-5f);
    Y[(size_t)row * DM + tid] = (x - m) * r * g[tid] + be[tid];
}

// ---------------- final projection at position 159 -> pred0 ----------------
__global__ __launch_bounds__(256) void final_k(const float* __restrict__ H,
        const float* __restrict__ fw, const float* __restrict__ fb,
        float* __restrict__ out) {
    int b = blockIdx.x;
    int tid = threadIdx.x;
    float v = H[(size_t)(b * ILEN + ILEN - 1) * DM + tid] * fw[tid];
#pragma unroll
    for (int o = 32; o > 0; o >>= 1) v += __shfl_xor(v, o);
    __shared__ float red[4];
    if ((tid & 63) == 0) red[tid >> 6] = v;
    __syncthreads();
    if (tid == 0)
        out[((size_t)b * TT + ILEN) * DIN] = red[0] + red[1] + red[2] + red[3] + fb[0];
}

// ================= decode v3: 4-block groups per batch, group barriers =================
__device__ inline void gbar(unsigned* __restrict__ c, unsigned target, int tid) {
    __syncthreads();
    if (tid == 0) {
        __hip_atomic_fetch_add(c, 1u, __ATOMIC_RELEASE, __HIP_MEMORY_SCOPE_AGENT);
        int guard = 0;
        while (__hip_atomic_load(c, __ATOMIC_ACQUIRE, __HIP_MEMORY_SCOPE_AGENT) < target) {
            __builtin_amdgcn_s_sleep(2);
            if (++guard > (1 << 27)) break;   // bail instead of hard hang
        }
    }
    __syncthreads();
}

__global__ __launch_bounds__(1024) void decode3_k(
        const float* __restrict__ X,
        const float* __restrict__ emb_w, const float* __restrict__ emb_b,
        const float* __restrict__ bq, const float* __restrict__ bk,
        const float* __restrict__ bv, const float* __restrict__ bo,
        const float* __restrict__ ln1g, const float* __restrict__ ln1b,
        const float* __restrict__ b1, const float* __restrict__ b2,
        const float* __restrict__ ln2g, const float* __restrict__ ln2b,
        const float* __restrict__ fw, const float* __restrict__ fb,
        const h2_t* __restrict__ qp_w, const h2_t* __restrict__ kp_w,
        const h2_t* __restrict__ vp_w, const h2_t* __restrict__ op_w,
        const h2_t* __restrict__ w1p, const h2_t* __restrict__ w2p,
        h2_t* __restrict__ K16, h2_t* __restrict__ V16,
        h2_t* __restrict__ q16, h2_t* __restrict__ ff16,
        float* __restrict__ pre1b, float* __restrict__ pre2b,
        unsigned* __restrict__ ctrs,
        float* __restrict__ out) {
    const int bid = blockIdx.x;
    const int b = bid & 63;        // batch
    const int m = bid >> 6;        // member 0..3 (same XCD for all members: bid%8==b%8)
    const int tid = threadIdx.x;
    const int wid = tid >> 6;
    const int lane = tid & 63;
    unsigned* ctr = ctrs + b;
    unsigned bt = 0;

    __shared__ float hs[256];      // current h (fp32)
    __shared__ h2_t h2l[128];      // current h packed
    __shared__ h2_t q2[128];       // q packed (scaled)
    __shared__ h2_t a2[128];       // attn out packed
    __shared__ float sc[NH][TT];   // attention scores
    __shared__ float scr[2048];    // split-K partials / PV partials
    __shared__ float tmp[256];     // phase outputs
    __shared__ float red[16], red2[16], hinv[8];

    float pred = out[((size_t)b * TT + ILEN) * DIN];   // pred0 from prefill

    for (int t = 0; t < TT - ILEN - 1; ++t) {   // 31 steps
        const int p = ILEN + t;
        // ---- embed (redundant per member) ----
        if (tid < 128) {
            float a0 = emb_b[2 * tid], a1 = emb_b[2 * tid + 1];
#pragma unroll
            for (int r = 0; r < DIN; ++r) {
                float xr = (r == 0) ? pred : X[((size_t)b * TT + p) * DIN + r];
                a0 += xr * emb_w[r * DM + 2 * tid];
                a1 += xr * emb_w[r * DM + 2 * tid + 1];
            }
            hs[2 * tid] = a0; hs[2 * tid + 1] = a1;
            h2_t v; v.x = (_Float16)a0; v.y = (_Float16)a1;
            h2l[tid] = v;
        }
        __syncthreads();

        for (int li = 0; li < NLAY; ++li) {
            const h2_t* wq2 = qp_w + (size_t)li * 32768;
            const h2_t* wk2 = kp_w + (size_t)li * 32768;
            const h2_t* wv2 = vp_w + (size_t)li * 32768;
            const h2_t* wo2 = op_w + (size_t)li * 32768;
            const h2_t* w12 = w1p + (size_t)li * 131072;
            const h2_t* w22 = w2p + (size_t)li * 131072;
            const size_t kvb = (size_t)(li * BN + b) * TT;   // row base (in 128-pair rows)

            // ---- QKV: member computes dims [m*64,(m+1)*64) of q,k,v; split-K 4 ----
            if (tid < 768) {
                int mat = tid >> 8;              // 0=q 1=k 2=v
                int r = tid & 255;
                int o = r & 63, kc = r >> 6;
                int og = m * 64 + o;
                const h2_t* w = (mat == 0) ? wq2 : (mat == 1) ? wk2 : wv2;
                float a = 0.f;
                int rp0 = kc * 32;
#pragma unroll 16
                for (int i = 0; i < 32; ++i)
                    a = FDOT2(h2l[rp0 + i], w[(size_t)(rp0 + i) * 256 + og], a);
                scr[tid] = a;  // [mat*256 + kc*64 + o]
            }
            __syncthreads();
            if (tid < 192) {
                int mat = tid >> 6, o = tid & 63;
                int og = m * 64 + o;
                float v = scr[mat * 256 + o] + scr[mat * 256 + 64 + o] +
                          scr[mat * 256 + 128 + o] + scr[mat * 256 + 192 + o];
                if (mat == 0) v = (v + bq[li * DM + og]) * SCALE;
                else if (mat == 1) v += bk[li * DM + og];
                else v += bv[li * DM + og];
                tmp[mat * 64 + o] = v;
            }
            __syncthreads();
            if (tid < 96) {
                int mat = tid >> 5, pl = tid & 31;
                h2_t v;
                v.x = (_Float16)tmp[mat * 64 + 2 * pl];
                v.y = (_Float16)tmp[mat * 64 + 2 * pl + 1];
                int pg = m * 32 + pl;
                if (mat == 0) q16[(size_t)b * 128 + pg] = v;
                else if (mat == 1) K16[(kvb + p) * 128 + pg] = v;
                else V16[(kvb + p) * 128 + pg] = v;
            }
            bt += GROUP; gbar(ctr, bt, tid);

            // ---- attention (redundant per member, all 8 heads) ----
            if (tid < 128) q2[tid] = q16[(size_t)b * 128 + tid];
            __syncthreads();
            {
                const int h = tid >> 7;
                const int js = tid & 127;
                float mx = -1e30f;
                for (int j = js; j <= p; j += 128) {
                    const h2_t* kr = K16 + (kvb + j) * 128 + h * 16;
                    float d = 0.f;
#pragma unroll
                    for (int i = 0; i < 16; ++i) d = FDOT2(q2[h * 16 + i], kr[i], d);
                    sc[h][j] = d;
                    mx = fmaxf(mx, d);
                }
#pragma unroll
                for (int o = 32; o > 0; o >>= 1) mx = fmaxf(mx, __shfl_xor(mx, o));
                if (lane == 0) red[wid] = mx;
                __syncthreads();
                mx = fmaxf(red[2 * h], red[2 * h + 1]);
                float sum = 0.f;
                for (int j = js; j <= p; j += 128) {
                    float e = __expf(sc[h][j] - mx);
                    sc[h][j] = e;
                    sum += e;
                }
#pragma unroll
                for (int o = 32; o > 0; o >>= 1) sum += __shfl_xor(sum, o);
                if (lane == 0) red2[wid] = sum;
                __syncthreads();
                if ((tid & 127) == 0) hinv[h] = 1.f / (red2[2 * h] + red2[2 * h + 1]);
                // PV: dp = dim-pair, jc = j-chunk
                int dp = js & 15, jc = js >> 4;
                float a0 = 0.f, a1 = 0.f;
                for (int j = jc; j <= p; j += 8) {
                    float pe = sc[h][j];
                    h2_t v = V16[(kvb + j) * 128 + h * 16 + dp];
                    a0 += pe * (float)v.x;
                    a1 += pe * (float)v.y;
                }
                scr[((h * 16 + dp) * 8 + jc) * 2 + 0] = a0;
                scr[((h * 16 + dp) * 8 + jc) * 2 + 1] = a1;
            }
            __syncthreads();
            if (tid < 256) {
                int h = tid >> 5, dl = tid & 31;
                int dp = dl >> 1, half = tid & 1;
                float s = 0.f;
#pragma unroll
                for (int jc = 0; jc < 8; ++jc)
                    s += scr[((h * 16 + dp) * 8 + jc) * 2 + half];
                tmp[tid] = s * hinv[h];
            }
            __syncthreads();
            if (tid < 128) {
                h2_t v; v.x = (_Float16)tmp[2 * tid]; v.y = (_Float16)tmp[2 * tid + 1];
                a2[tid] = v;
            }
            __syncthreads();

            // ---- O proj: member dims [m*64,..); split-K 8 ----
            if (tid < 512) {
                int o = tid & 63, kc = tid >> 6;
                int og = m * 64 + o;
                float a = 0.f;
                int rp0 = kc * 16;
#pragma unroll
                for (int i = 0; i < 16; ++i)
                    a = FDOT2(a2[rp0 + i], wo2[(size_t)(rp0 + i) * 256 + og], a);
                scr[kc * 64 + o] = a;
            }
            __syncthreads();
            if (tid < 64) {
                int og = m * 64 + tid;
                float v = bo[li * DM + og] + hs[og];
#pragma unroll
                for (int kc = 0; kc < 8; ++kc) v += scr[kc * 64 + tid];
                pre1b[(size_t)b * DM + og] = v;
            }
            bt += GROUP; gbar(ctr, bt, tid);

            // ---- LN1 (redundant) ----
            {
                float x = (tid < 256) ? pre1b[(size_t)b * DM + tid] : 0.f;
                float s = x, s2 = x * x;
#pragma unroll
                for (int o = 32; o > 0; o >>= 1) { s += __shfl_xor(s, o); s2 += __shfl_xor(s2, o); }
                if (lane == 0) { red[wid] = s; red2[wid] = s2; }
                __syncthreads();
                if (tid < 256) {
                    float S = red[0] + red[1] + red[2] + red[3];
                    float S2 = red2[0] + red2[1] + red2[2] + red2[3];
                    float mu = S * (1.f / 256.f);
                    float var = S2 * (1.f / 256.f) - mu * mu;
                    float rr = rsqrtf(var + 1e-5f);
                    hs[tid] = (x - mu) * rr * ln1g[li * DM + tid] + ln1b[li * DM + tid];
                }
                __syncthreads();
                if (tid < 128) {
                    h2_t v; v.x = (_Float16)hs[2 * tid]; v.y = (_Float16)hs[2 * tid + 1];
                    h2l[tid] = v;
                }
                __syncthreads();
            }
            // ---- FFN1: member dims [m*256,..); split-K 4 ----
            {
                int o = tid & 255, kc = tid >> 8;
                int og = m * 256 + o;
                float a = 0.f;
                int rp0 = kc * 32;
#pragma unroll 16
                for (int i = 0; i < 32; ++i)
                    a = FDOT2(h2l[rp0 + i], w12[(size_t)(rp0 + i) * 1024 + og], a);
                scr[kc * 256 + o] = a;
            }
            __syncthreads();
            if (tid < 256) {
                int og = m * 256 + tid;
                float v = b1[li * DFF + og] + scr[tid] + scr[256 + tid] +
                          scr[512 + tid] + scr[768 + tid];
                tmp[tid] = fmaxf(v, 0.f);
            }
            __syncthreads();
            if (tid < 128) {
                h2_t v; v.x = (_Float16)tmp[2 * tid]; v.y = (_Float16)tmp[2 * tid + 1];
                ff16[(size_t)b * 512 + m * 128 + tid] = v;
            }
            bt += GROUP; gbar(ctr, bt, tid);

            // ---- FFN2: member dims [m*64,..); split-K 16 over 512 pairs ----
            {
                int o = tid & 63, kc = tid >> 6;
                int og = m * 64 + o;
                float a = 0.f;
                int rp0 = kc * 32;
#pragma unroll 16
                for (int i = 0; i < 32; ++i)
                    a = FDOT2(ff16[(size_t)b * 512 + rp0 + i],
                              w22[(size_t)(rp0 + i) * 256 + og], a);
                scr[kc * 64 + o] = a;
            }
            __syncthreads();
            if (tid < 64) {
                int og = m * 64 + tid;
                float v = b2[li * DM + og] + hs[og];
#pragma unroll
                for (int kc = 0; kc < 16; ++kc) v += scr[kc * 64 + tid];
                pre2b[(size_t)b * DM + og] = v;
            }
            bt += GROUP; gbar(ctr, bt, tid);

            // ---- LN2 (redundant) ----
            {
                float x = (tid < 256) ? pre2b[(size_t)b * DM + tid] : 0.f;
                float s = x, s2 = x * x;
#pragma unroll
                for (int o = 32; o > 0; o >>= 1) { s += __shfl_xor(s, o); s2 += __shfl_xor(s2, o); }
                if (lane == 0) { red[wid] = s; red2[wid] = s2; }
                __syncthreads();
                if (tid < 256) {
                    float S = red[0] + red[1] + red[2] + red[3];
                    float S2 = red2[0] + red2[1] + red2[2] + red2[3];
                    float mu = S * (1.f / 256.f);
                    float var = S2 * (1.f / 256.f) - mu * mu;
                    float rr = rsqrtf(var + 1e-5f);
                    hs[tid] = (x - mu) * rr * ln2g[li * DM + tid] + ln2b[li * DM + tid];
                }
                __syncthreads();
                if (tid < 128) {
                    h2_t v; v.x = (_Float16)hs[2 * tid]; v.y = (_Float16)hs[2 * tid + 1];
                    h2l[tid] = v;
                }
                __syncthreads();
            }
        }
        // ---- final projection (redundant) -> next pred ----
        {
            float v = (tid < 256) ? hs[tid] * fw[tid] : 0.f;
#pragma unroll
            for (int o = 32; o > 0; o >>= 1) v += __shfl_xor(v, o);
            if (lane == 0) red[wid] = v;
            __syncthreads();
            pred = red[0] + red[1] + red[2] + red[3] + fb[0];
            if (m == 0 && tid == 0)
                out[((size_t)b * TT + p + 1) * DIN] = pred;
            __syncthreads();   // hs reused next step
        }
    }
}

extern "C" void kernel_launch(void* const* d_in, const int* in_sizes, int n_in,
                              void* d_out, int out_size, void* d_ws, size_t ws_size,
                              hipStream_t stream) {
    const float* X     = (const float*)d_in[0];
    const float* emb_w = (const float*)d_in[1];
    const float* emb_b = (const float*)d_in[2];
    const float* Wq    = (const float*)d_in[3];
    const float* bq    = (const float*)d_in[4];
    const float* Wk    = (const float*)d_in[5];
    const float* bk    = (const float*)d_in[6];
    const float* Wv    = (const float*)d_in[7];
    const float* bv    = (const float*)d_in[8];
    const float* Wo    = (const float*)d_in[9];
    const float* bo    = (const float*)d_in[10];
    const float* ln1g  = (const float*)d_in[11];
    const float* ln1b  = (const float*)d_in[12];
    const float* W1    = (const float*)d_in[13];
    const float* b1    = (const float*)d_in[14];
    const float* W2    = (const float*)d_in[15];
    const float* b2    = (const float*)d_in[16];
    const float* ln2g  = (const float*)d_in[17];
    const float* ln2b  = (const float*)d_in[18];
    const float* fw    = (const float*)d_in[19];
    const float* fb    = (const float*)d_in[20];
    float* out = (float*)d_out;

    // workspace layout (floats)
    float* ws = (float*)d_ws;
    const size_t HROWS = (size_t)PRE_ROWS * DM;        // 2,621,440
    float* h   = ws;
    float* qa  = ws + HROWS;
    float* pre = ws + 2 * HROWS;                       // prefill-only
    float* ff  = ws + 3 * HROWS;                       // prefill-only
    float* Kc  = ws + 3 * HROWS + (size_t)PRE_ROWS * DFF;
    float* Vc  = Kc + (size_t)NLAY * BN * TT * DM;
    const size_t LSL = (size_t)BN * TT * DM;
    // f16 KV overlays the dead prefill pre+ff region (52.4MB >= 50.4MB)
    h2_t* K16 = (h2_t*)pre;
    h2_t* V16 = K16 + (size_t)NLAY * BN * TT * 128;    // 6,291,456 h2 each
    // packed f16 weights after Vc
    float* pk_base = Vc + (size_t)NLAY * BN * TT * DM;
    h2_t* embp = (h2_t*)pk_base;
    h2_t* qp   = embp + 1024;
    h2_t* kp   = qp + 131072;
    h2_t* vp   = kp + 131072;
    h2_t* op   = vp + 131072;
    h2_t* w1p  = op + 131072;
    h2_t* w2p  = w1p + 524288;
    h2_t* pk_end = w2p + 524288;
    // decode comm buffers
    h2_t* q16   = pk_end;                              // 64 x 128
    h2_t* ff16  = q16 + 64 * 128;                      // 64 x 512
    float* pre1b = (float*)(ff16 + 64 * 512);          // 64 x 256
    float* pre2b = pre1b + 64 * 256;
    unsigned* ctrs = (unsigned*)(pre2b + 64 * 256);    // 64 counters

    // pack weights
    pack_k<<<dim3(1, 4),    256, 0, stream>>>(emb_w, embp, DM);
    pack_k<<<dim3(1, 512),  256, 0, stream>>>(Wq, qp, DM);
    pack_k<<<dim3(1, 512),  256, 0, stream>>>(Wk, kp, DM);
    pack_k<<<dim3(1, 512),  256, 0, stream>>>(Wv, vp, DM);
    pack_k<<<dim3(1, 512),  256, 0, stream>>>(Wo, op, DM);
    pack_k<<<dim3(4, 512),  256, 0, stream>>>(W1, w1p, DFF);
    pack_k<<<dim3(1, 2048), 256, 0, stream>>>(W2, w2p, DM);
    init_ctr_k<<<1, 64, 0, stream>>>(ctrs);

    copy_out_k<<<(BN * TT * DIN + 255) / 256, 256, 0, stream>>>(X, out, BN * TT * DIN);
    embed_k<<<PRE_ROWS, 256, 0, stream>>>(X, emb_w, emb_b, h);

    for (int li = 0; li < NLAY; ++li) {
        const float* wq = Wq + (size_t)li * DM * DM;
        const float* wk = Wk + (size_t)li * DM * DM;
        const float* wv = Wv + (size_t)li * DM * DM;
        const float* wo = Wo + (size_t)li * DM * DM;
        const float* w1 = W1 + (size_t)li * DM * DFF;
        const float* w2 = W2 + (size_t)li * DFF * DM;
        gemm_k<<<dim3(4, 160), 256, 0, stream>>>(h, wq, bq + li * DM, nullptr, qa,
                                                 PRE_ROWS, DM, DM, 0, 0);
        gemm_k<<<dim3(4, 160), 256, 0, stream>>>(h, wk, bk + li * DM, nullptr, Kc + li * LSL,
                                                 PRE_ROWS, DM, DM, 0, 1);
        gemm_k<<<dim3(4, 160), 256, 0, stream>>>(h, wv, bv + li * DM, nullptr, Vc + li * LSL,
                                                 PRE_ROWS, DM, DM, 0, 1);
        attn_k<<<dim3(ILEN, BN), 256, 0, stream>>>(qa, Kc + li * LSL, Vc + li * LSL, qa);
        gemm_k<<<dim3(4, 160), 256, 0, stream>>>(qa, wo, bo + li * DM, h, pre,
                                                 PRE_ROWS, DM, DM, 2, 0);
        ln_k<<<PRE_ROWS, 256, 0, stream>>>(pre, ln1g + li * DM, ln1b + li * DM, h);
        gemm_k<<<dim3(16, 160), 256, 0, stream>>>(h, w1, b1 + li * DFF, nullptr, ff,
                                                  PRE_ROWS, DFF, DM, 1, 0);
        gemm_k<<<dim3(4, 160), 256, 0, stream>>>(ff, w2, b2 + li * DM, h, pre,
                                                 PRE_ROWS, DM, DFF, 2, 0);
        ln_k<<<PRE_ROWS, 256, 0, stream>>>(pre, ln2g + li * DM, ln2b + li * DM, h);
    }
    final_k<<<BN, 256, 0, stream>>>(h, fw, fb, out);

    // convert prefill KV to f16 (pre/ff are dead now; K16/V16 overlay them)
    kvconv_k<<<20480, 256, 0, stream>>>(Kc, Vc, K16, V16);

    decode3_k<<<BN * GROUP, 1024, 0, stream>>>(X, emb_w, emb_b, bq, bk, bv, bo,
                                               ln1g, ln1b, b1, b2, ln2g, ln2b, fw, fb,
                                               qp, kp, vp, op, w1p, w2p,
                                               K16, V16, q16, ff16, pre1b, pre2b, ctrs,
                                               out);
}

// Round 4
// 7012.525 us; speedup vs baseline: 2.4556x; 1.3619x over previous
//
#include <hip/hip_runtime.h>
#include <hip/hip_bf16.h>

// Model dims
#define BN 64      // batch
#define TT 192     // total seq
#define ILEN 160   // input_len
#define DIN 8
#define DM 256
#define NH 8
#define DH 32
#define DFF 1024
#define NLAY 4
#define PRE_ROWS (BN * ILEN)   // 10240
#define SCALE 0.17677669529663687f  // 1/sqrt(32)
#define GROUP 4                // decode blocks per batch

typedef _Float16 h2_t __attribute__((ext_vector_type(2)));

#if defined(__has_builtin)
#if __has_builtin(__builtin_amdgcn_fdot2)
#define FDOT2(a, b, c) __builtin_amdgcn_fdot2((a), (b), (c), false)
#endif
#endif
#ifndef FDOT2
static __device__ inline float fdot2_fb(h2_t a, h2_t b, float c) {
    return c + (float)a.x * (float)b.x + (float)a.y * (float)b.y;
}
#define FDOT2(a, b, c) fdot2_fb((a), (b), (c))
#endif

// ---------------- copy whole_example -> out ----------------
__global__ void copy_out_k(const float* __restrict__ X, float* __restrict__ O, int n) {
    int i = blockIdx.x * blockDim.x + threadIdx.x;
    if (i < n) O[i] = X[i];
}

// ---------------- zero the group-barrier counters ----------------
__global__ void init_ctr_k(unsigned* __restrict__ ctr) {
    if (threadIdx.x < BN) ctr[threadIdx.x] = 0u;
}

// ---------------- pack fp32 [2*Rp][N] -> half2 [Rp][N] ----------------
__global__ __launch_bounds__(256) void pack_k(const float* __restrict__ src,
        h2_t* __restrict__ dst, int N) {
    int o = blockIdx.x * 256 + threadIdx.x;
    int rp = blockIdx.y;
    if (o < N) {
        h2_t v;
        v.x = (_Float16)src[(size_t)(2 * rp) * N + o];
        v.y = (_Float16)src[(size_t)(2 * rp + 1) * N + o];
        dst[(size_t)rp * N + o] = v;
    }
}

// ---------------- convert prefill fp32 KV (rows 0..159) -> f16 pairs ----------------
__global__ __launch_bounds__(256) void kvconv_k(const float* __restrict__ Kc,
        const float* __restrict__ Vc, h2_t* __restrict__ K16, h2_t* __restrict__ V16) {
    size_t i = (size_t)blockIdx.x * 256 + threadIdx.x;
    int pi = i & 127;
    size_t r = i >> 7;
    int j = (int)(r % ILEN);
    size_t lb = r / ILEN;
    size_t src = (lb * TT + j) * DM + 2 * pi;
    size_t dst = (lb * TT + j) * (DM / 2) + pi;
    h2_t k, v;
    k.x = (_Float16)Kc[src]; k.y = (_Float16)Kc[src + 1];
    v.x = (_Float16)Vc[src]; v.y = (_Float16)Vc[src + 1];
    K16[dst] = k;
    V16[dst] = v;
}

// ---------------- embedding for prefill rows ----------------
__global__ __launch_bounds__(256) void embed_k(const float* __restrict__ X,
        const float* __restrict__ w, const float* __restrict__ bias,
        float* __restrict__ H) {
    int row = blockIdx.x;
    int b = row / ILEN, p = row % ILEN;
    int tid = threadIdx.x;
    const float* x = X + (size_t)(b * TT + p) * DIN;
    float acc = bias[tid];
#pragma unroll
    for (int r = 0; r < DIN; ++r) acc += x[r] * w[r * DM + tid];
    H[(size_t)row * DM + tid] = acc;
}

// ---------------- generic fp32 tiled GEMM (prefill) ----------------
__global__ __launch_bounds__(256) void gemm_k(
        const float* __restrict__ A, const float* __restrict__ W,
        const float* __restrict__ bias, const float* __restrict__ R,
        float* __restrict__ C, int M, int N, int K, int mode, int remap) {
    __shared__ float As[16][64];
    __shared__ float Bs[16][64];
    int tid = threadIdx.x;
    int bx = blockIdx.x, by = blockIdx.y;
    int tx = tid & 15, ty = tid >> 4;
    int row0 = by * 64 + ty * 4;
    int col0 = bx * 64 + tx * 4;
    float acc[4][4] = {};
    int arow = tid >> 2, ak4 = tid & 3;
    int brow = tid >> 4, bc4 = tid & 15;
    const float* aptr = A + (size_t)(by * 64 + arow) * K + ak4 * 4;
    const float* bptr = W + (size_t)brow * N + bx * 64 + bc4 * 4;
    for (int kt = 0; kt < K; kt += 16) {
        float4 av = *(const float4*)(aptr + kt);
        float4 bv = *(const float4*)(bptr + (size_t)kt * N);
        As[ak4 * 4 + 0][arow] = av.x;
        As[ak4 * 4 + 1][arow] = av.y;
        As[ak4 * 4 + 2][arow] = av.z;
        As[ak4 * 4 + 3][arow] = av.w;
        *(float4*)&Bs[brow][bc4 * 4] = bv;
        __syncthreads();
#pragma unroll
        for (int k = 0; k < 16; ++k) {
            float a[4], bb[4];
#pragma unroll
            for (int i = 0; i < 4; ++i) a[i] = As[k][ty * 4 + i];
#pragma unroll
            for (int j = 0; j < 4; ++j) bb[j] = Bs[k][tx * 4 + j];
#pragma unroll
            for (int i = 0; i < 4; ++i)
#pragma unroll
                for (int j = 0; j < 4; ++j) acc[i][j] += a[i] * bb[j];
        }
        __syncthreads();
    }
#pragma unroll
    for (int i = 0; i < 4; ++i) {
        int row = row0 + i;
        int orow = remap ? (row / ILEN) * TT + (row % ILEN) : row;
#pragma unroll
        for (int j = 0; j < 4; ++j) {
            int col = col0 + j;
            float v = acc[i][j] + bias[col];
            if (mode == 1) v = fmaxf(v, 0.f);
            if (mode == 2) v += R[(size_t)row * N + col];
            C[(size_t)orow * N + col] = v;
        }
    }
}

// ---------------- prefill attention ----------------
__global__ __launch_bounds__(256) void attn_k(
        const float* __restrict__ Q, const float* __restrict__ Kc,
        const float* __restrict__ Vc, float* __restrict__ O) {
    int qp = blockIdx.x;
    int b = blockIdx.y;
    int tid = threadIdx.x;
    int hh = tid >> 5, l = tid & 31;
    __shared__ float qs[DM];
    __shared__ float sc[NH][TT];
    int qrow = b * ILEN + qp;
    qs[tid] = Q[(size_t)qrow * DM + tid] * SCALE;
    __syncthreads();
    const float* Kb = Kc + (size_t)b * TT * DM;
    const float* Vb = Vc + (size_t)b * TT * DM;
    float mx = -1e30f;
    for (int j = l; j <= qp; j += 32) {
        const float* kr = Kb + (size_t)j * DM + hh * DH;
        float d = 0.f;
#pragma unroll
        for (int u = 0; u < DH; ++u) d += qs[hh * DH + u] * kr[u];
        sc[hh][j] = d;
        mx = fmaxf(mx, d);
    }
#pragma unroll
    for (int o = 16; o > 0; o >>= 1) mx = fmaxf(mx, __shfl_xor(mx, o, 32));
    float sum = 0.f;
    for (int j = l; j <= qp; j += 32) {
        float p = __expf(sc[hh][j] - mx);
        sc[hh][j] = p;
        sum += p;
    }
#pragma unroll
    for (int o = 16; o > 0; o >>= 1) sum += __shfl_xor(sum, o, 32);
    float inv = 1.f / sum;
    float acc = 0.f;
    for (int j = 0; j <= qp; ++j)
        acc += sc[hh][j] * Vb[(size_t)j * DM + hh * DH + l];
    O[(size_t)qrow * DM + hh * DH + l] = acc * inv;
}

// ---------------- layernorm over rows of 256 (prefill) ----------------
__global__ __launch_bounds__(256) void ln_k(const float* __restrict__ Xp,
        const float* __restrict__ g, const float* __restrict__ be,
        float* __restrict__ Y) {
    int row = blockIdx.x;
    int tid = threadIdx.x;
    float x = Xp[(size_t)row * DM + tid];
    float s = x, s2 = x * x;
#pragma unroll
    for (int o = 32; o > 0; o >>= 1) { s += __shfl_xor(s, o); s2 += __shfl_xor(s2, o); }
    __shared__ float red[8];
    if ((tid & 63) == 0) { red[tid >> 6] = s; red[4 + (tid >> 6)] = s2; }
    __syncthreads();
    s = red[0] + red[1] + red[2] + red[3];
    s2 = red[4] + red[5] + red[6] + red[7];
    float m = s * (1.f / 256.f);
    float var = s2 * (1.f / 256.f) - m * m;
    float r = rsqrtf(var + 1e-5f);
    Y[(size_t)row * DM + tid] = (x - m) * r * g[tid] + be[tid];
}

// ---------------- final projection at position 159 -> pred0 ----------------
__global__ __launch_bounds__(256) void final_k(const float* __restrict__ H,
        const float* __restrict__ fw, const float* __restrict__ fb,
        float* __restrict__ out) {
    int b = blockIdx.x;
    int tid = threadIdx.x;
    float v = H[(size_t)(b * ILEN + ILEN - 1) * DM + tid] * fw[tid];
#pragma unroll
    for (int o = 32; o > 0; o >>= 1) v += __shfl_xor(v, o);
    __shared__ float red[4];
    if ((tid & 63) == 0) red[tid >> 6] = v;
    __syncthreads();
    if (tid == 0)
        out[((size_t)b * TT + ILEN) * DIN] = red[0] + red[1] + red[2] + red[3] + fb[0];
}

// ================= decode v4: head-local attention, 2 barriers/layer =================
__device__ inline void gbar(unsigned* __restrict__ c, unsigned target, int tid) {
    __syncthreads();
    if (tid == 0) {
        __hip_atomic_fetch_add(c, 1u, __ATOMIC_RELEASE, __HIP_MEMORY_SCOPE_AGENT);
        int guard = 0;
        while (__hip_atomic_load(c, __ATOMIC_ACQUIRE, __HIP_MEMORY_SCOPE_AGENT) < target) {
            __builtin_amdgcn_s_sleep(1);
            if (++guard > (1 << 27)) break;   // bail instead of hard hang
        }
    }
    __syncthreads();
}

__global__ __launch_bounds__(1024, 4) void decode4_k(
        const float* __restrict__ X,
        const float* __restrict__ emb_w, const float* __restrict__ emb_b,
        const float* __restrict__ bq, const float* __restrict__ bk,
        const float* __restrict__ bv, const float* __restrict__ bo,
        const float* __restrict__ ln1g, const float* __restrict__ ln1b,
        const float* __restrict__ b1, const float* __restrict__ b2,
        const float* __restrict__ ln2g, const float* __restrict__ ln2b,
        const float* __restrict__ fw, const float* __restrict__ fb,
        const h2_t* __restrict__ qp_w, const h2_t* __restrict__ kp_w,
        const h2_t* __restrict__ vp_w, const h2_t* __restrict__ op_w,
        const h2_t* __restrict__ w1p, const h2_t* __restrict__ w2p,
        h2_t* __restrict__ K16, h2_t* __restrict__ V16,
        float* __restrict__ opart, float* __restrict__ f2part,
        unsigned* __restrict__ ctrs,
        float* __restrict__ out) {
    const int bid = blockIdx.x;
    const int b = bid & 63;        // batch
    const int m = bid >> 6;        // member 0..3 (same XCD: bid%8 == b%8)
    const int tid = threadIdx.x;
    const int wid = tid >> 6;
    const int lane = tid & 63;
    unsigned* ctr = ctrs + b;
    unsigned bt = 0;

    __shared__ float hs[256];          // residual stream (fp32)
    __shared__ h2_t h2l[128];          // h packed
    __shared__ h2_t q2[32], kp_l[32], vp_l[32], a2l[32], ff_l[128];
    __shared__ float sc[2][TT];        // scores for my 2 heads
    __shared__ float scr[2048];        // split-K / PV partials
    __shared__ float tmp[256];
    __shared__ float red[16], red2[16];

    float pred = out[((size_t)b * TT + ILEN) * DIN];   // pred0 from prefill

    for (int t = 0; t < TT - ILEN - 1; ++t) {   // 31 steps
        const int p = ILEN + t;
        __syncthreads();
        // ---- embed (redundant per member, block-local) ----
        if (tid < 128) {
            float a0 = emb_b[2 * tid], a1 = emb_b[2 * tid + 1];
#pragma unroll
            for (int r = 0; r < DIN; ++r) {
                float xr = (r == 0) ? pred : X[((size_t)b * TT + p) * DIN + r];
                a0 += xr * emb_w[r * DM + 2 * tid];
                a1 += xr * emb_w[r * DM + 2 * tid + 1];
            }
            hs[2 * tid] = a0; hs[2 * tid + 1] = a1;
            h2_t v; v.x = (_Float16)a0; v.y = (_Float16)a1;
            h2l[tid] = v;
        }
        __syncthreads();

        for (int li = 0; li < NLAY; ++li) {
            const h2_t* wq2 = qp_w + (size_t)li * 32768;
            const h2_t* wk2 = kp_w + (size_t)li * 32768;
            const h2_t* wv2 = vp_w + (size_t)li * 32768;
            const h2_t* wo2 = op_w + (size_t)li * 32768;
            const h2_t* w12 = w1p + (size_t)li * 131072;
            const h2_t* w22 = w2p + (size_t)li * 131072;
            const size_t kvb = (size_t)(li * BN + b) * TT;

            // ---- A: QKV for my 64 dims (heads 2m,2m+1); no barrier needed ----
            if (tid < 768) {
                int mat = tid >> 8, o = tid & 63, kc = (tid >> 6) & 3;
                const h2_t* w = (mat == 0) ? wq2 : (mat == 1) ? wk2 : wv2;
                const h2_t* wp = w + (size_t)(kc * 32) * 256 + m * 64 + o;
                float a = 0.f;
#pragma unroll
                for (int i = 0; i < 32; ++i)
                    a = FDOT2(h2l[kc * 32 + i], wp[(size_t)i * 256], a);
                scr[mat * 256 + kc * 64 + o] = a;
            }
            __syncthreads();
            if (tid < 192) {
                int mat = tid >> 6, o = tid & 63, og = m * 64 + o;
                float v = scr[mat * 256 + o] + scr[mat * 256 + 64 + o] +
                          scr[mat * 256 + 128 + o] + scr[mat * 256 + 192 + o];
                if (mat == 0) v = (v + bq[li * DM + og]) * SCALE;
                else if (mat == 1) v += bk[li * DM + og];
                else v += bv[li * DM + og];
                tmp[mat * 64 + o] = v;
            }
            __syncthreads();
            if (tid < 96) {
                int mat = tid >> 5, pl = tid & 31;
                h2_t v;
                v.x = (_Float16)tmp[mat * 64 + 2 * pl];
                v.y = (_Float16)tmp[mat * 64 + 2 * pl + 1];
                if (mat == 0) q2[pl] = v;
                else if (mat == 1) { kp_l[pl] = v; K16[(kvb + p) * 128 + m * 32 + pl] = v; }
                else { vp_l[pl] = v; V16[(kvb + p) * 128 + m * 32 + pl] = v; }
            }
            __syncthreads();

            // ---- B: attention for my 2 heads (512 threads each), all local ----
            {
                const int hl = tid >> 9;            // 0..1
                const int u = tid & 511;
                const int kb = m * 32 + hl * 16;    // pair base of head in KV row
                float mval = -1e30f;
                if (u < TT && u <= p) {
                    float d = 0.f;
                    if (u == p) {
#pragma unroll
                        for (int i = 0; i < 16; ++i)
                            d = FDOT2(q2[hl * 16 + i], kp_l[hl * 16 + i], d);
                    } else {
                        const h2_t* kr = K16 + (kvb + u) * 128 + kb;
#pragma unroll
                        for (int i = 0; i < 16; ++i)
                            d = FDOT2(q2[hl * 16 + i], kr[i], d);
                    }
                    sc[hl][u] = d;
                    mval = d;
                }
#pragma unroll
                for (int o = 32; o > 0; o >>= 1) mval = fmaxf(mval, __shfl_xor(mval, o));
                if (lane == 0) red[wid] = mval;
                __syncthreads();
                float mx = fmaxf(fmaxf(red[8 * hl], red[8 * hl + 1]), red[8 * hl + 2]);
                float sval = 0.f;
                if (u < TT && u <= p) {
                    float e = __expf(sc[hl][u] - mx);
                    sc[hl][u] = e;
                    sval = e;
                }
#pragma unroll
                for (int o = 32; o > 0; o >>= 1) sval += __shfl_xor(sval, o);
                if (lane == 0) red2[wid] = sval;
                __syncthreads();
                // PV: dp = pair in head (16), jc = j-chunk (32); 6 fixed iters
                int dp = u & 15, jc = u >> 4;
                float a0 = 0.f, a1 = 0.f;
#pragma unroll
                for (int it = 0; it < 6; ++it) {
                    int j = jc + 32 * it;
                    bool ok = (j <= p);
                    float pe = ok ? sc[hl][j] : 0.f;
                    float vx = 0.f, vy = 0.f;
                    if (ok) {
                        h2_t v = (j == p) ? vp_l[hl * 16 + dp]
                                          : V16[(kvb + j) * 128 + kb + dp];
                        vx = (float)v.x; vy = (float)v.y;
                    }
                    a0 += pe * vx; a1 += pe * vy;
                }
                scr[((hl * 16 + dp) * 32 + jc) * 2 + 0] = a0;
                scr[((hl * 16 + dp) * 32 + jc) * 2 + 1] = a1;
            }
            __syncthreads();
            if (tid < 128) {           // partial jc-reduce: pp(32) x qq(4)
                int pp = tid & 31, qq = tid >> 5;
                float a0 = 0.f, a1 = 0.f;
#pragma unroll
                for (int r = 0; r < 8; ++r) {
                    int jc = qq * 8 + r;
                    a0 += scr[(pp * 32 + jc) * 2 + 0];
                    a1 += scr[(pp * 32 + jc) * 2 + 1];
                }
                tmp[qq * 64 + 2 * pp] = a0;
                tmp[qq * 64 + 2 * pp + 1] = a1;
            }
            __syncthreads();
            if (tid < 32) {
                int hl = tid >> 4;
                float inv = 1.f / (red2[8 * hl] + red2[8 * hl + 1] + red2[8 * hl + 2]);
                float a0 = tmp[2 * tid] + tmp[64 + 2 * tid] + tmp[128 + 2 * tid] + tmp[192 + 2 * tid];
                float a1 = tmp[2 * tid + 1] + tmp[64 + 2 * tid + 1] + tmp[128 + 2 * tid + 1] + tmp[192 + 2 * tid + 1];
                h2_t v; v.x = (_Float16)(a0 * inv); v.y = (_Float16)(a1 * inv);
                a2l[tid] = v;
            }
            __syncthreads();

            // ---- C: O-projection partial (my 32 attn pairs x all 256 outputs) ----
            {
                int o = tid & 255, kc = tid >> 8;
                const h2_t* wp = wo2 + (size_t)(m * 32 + kc * 8) * 256 + o;
                float a = 0.f;
#pragma unroll
                for (int i = 0; i < 8; ++i)
                    a = FDOT2(a2l[kc * 8 + i], wp[(size_t)i * 256], a);
                scr[kc * 256 + o] = a;
            }
            __syncthreads();
            if (tid < 256)
                opart[((size_t)b * GROUP + m) * DM + tid] =
                    scr[tid] + scr[256 + tid] + scr[512 + tid] + scr[768 + tid];
            bt += GROUP; gbar(ctr, bt, tid);

            // ---- D: residual + LN1 (redundant) ----
            {
                float x = 0.f;
                if (tid < 256) {
                    x = hs[tid] + bo[li * DM + tid];
                    const float* opb = opart + (size_t)b * GROUP * DM + tid;
#pragma unroll
                    for (int mm = 0; mm < GROUP; ++mm) x += opb[mm * DM];
                }
                float s = x, s2 = x * x;
#pragma unroll
                for (int o = 32; o > 0; o >>= 1) { s += __shfl_xor(s, o); s2 += __shfl_xor(s2, o); }
                if (tid < 256 && lane == 0) { red[wid] = s; red2[wid] = s2; }
                __syncthreads();
                if (tid < 256) {
                    float S = red[0] + red[1] + red[2] + red[3];
                    float S2 = red2[0] + red2[1] + red2[2] + red2[3];
                    float mu = S * (1.f / 256.f);
                    float var = S2 * (1.f / 256.f) - mu * mu;
                    float rr = rsqrtf(var + 1e-5f);
                    hs[tid] = (x - mu) * rr * ln1g[li * DM + tid] + ln1b[li * DM + tid];
                }
                __syncthreads();
                if (tid < 128) {
                    h2_t v; v.x = (_Float16)hs[2 * tid]; v.y = (_Float16)hs[2 * tid + 1];
                    h2l[tid] = v;
                }
                __syncthreads();
            }
            // ---- E: FFN1 (+relu), my 256 of 1024 outputs; no barrier ----
            {
                int o = tid & 255, kc = tid >> 8;
                const h2_t* wp = w12 + (size_t)(kc * 32) * 1024 + m * 256 + o;
                float a = 0.f;
#pragma unroll
                for (int i = 0; i < 32; ++i)
                    a = FDOT2(h2l[kc * 32 + i], wp[(size_t)i * 1024], a);
                scr[kc * 256 + o] = a;
            }
            __syncthreads();
            if (tid < 256) {
                float v = b1[li * DFF + m * 256 + tid] +
                          scr[tid] + scr[256 + tid] + scr[512 + tid] + scr[768 + tid];
                tmp[tid] = fmaxf(v, 0.f);
            }
            __syncthreads();
            if (tid < 128) {
                h2_t v; v.x = (_Float16)tmp[2 * tid]; v.y = (_Float16)tmp[2 * tid + 1];
                ff_l[tid] = v;
            }
            __syncthreads();
            // ---- F: FFN2 partial over my own ff slice (pairs [128m,128m+128)) ----
            {
                int o = tid & 255, kc = tid >> 8;
                const h2_t* wp = w22 + (size_t)(m * 128 + kc * 32) * 256 + o;
                float a = 0.f;
#pragma unroll
                for (int i = 0; i < 32; ++i)
                    a = FDOT2(ff_l[kc * 32 + i], wp[(size_t)i * 256], a);
                scr[kc * 256 + o] = a;
            }
            __syncthreads();
            if (tid < 256)
                f2part[((size_t)b * GROUP + m) * DM + tid] =
                    scr[tid] + scr[256 + tid] + scr[512 + tid] + scr[768 + tid];
            bt += GROUP; gbar(ctr, bt, tid);

            // ---- G: residual + LN2 (redundant) ----
            {
                float x = 0.f;
                if (tid < 256) {
                    x = hs[tid] + b2[li * DM + tid];
                    const float* fpb = f2part + (size_t)b * GROUP * DM + tid;
#pragma unroll
                    for (int mm = 0; mm < GROUP; ++mm) x += fpb[mm * DM];
                }
                float s = x, s2 = x * x;
#pragma unroll
                for (int o = 32; o > 0; o >>= 1) { s += __shfl_xor(s, o); s2 += __shfl_xor(s2, o); }
                if (tid < 256 && lane == 0) { red[wid] = s; red2[wid] = s2; }
                __syncthreads();
                if (tid < 256) {
                    float S = red[0] + red[1] + red[2] + red[3];
                    float S2 = red2[0] + red2[1] + red2[2] + red2[3];
                    float mu = S * (1.f / 256.f);
                    float var = S2 * (1.f / 256.f) - mu * mu;
                    float rr = rsqrtf(var + 1e-5f);
                    hs[tid] = (x - mu) * rr * ln2g[li * DM + tid] + ln2b[li * DM + tid];
                }
                __syncthreads();
                if (tid < 128) {
                    h2_t v; v.x = (_Float16)hs[2 * tid]; v.y = (_Float16)hs[2 * tid + 1];
                    h2l[tid] = v;
                }
                __syncthreads();
            }
        }
        // ---- final projection (redundant) -> next pred ----
        {
            float v = (tid < 256) ? hs[tid] * fw[tid] : 0.f;
#pragma unroll
            for (int o = 32; o > 0; o >>= 1) v += __shfl_xor(v, o);
            if (tid < 256 && lane == 0) red[wid] = v;
            __syncthreads();
            pred = red[0] + red[1] + red[2] + red[3] + fb[0];
            if (m == 0 && tid == 0)
                out[((size_t)b * TT + p + 1) * DIN] = pred;
        }
    }
}

extern "C" void kernel_launch(void* const* d_in, const int* in_sizes, int n_in,
                              void* d_out, int out_size, void* d_ws, size_t ws_size,
                              hipStream_t stream) {
    const float* X     = (const float*)d_in[0];
    const float* emb_w = (const float*)d_in[1];
    const float* emb_b = (const float*)d_in[2];
    const float* Wq    = (const float*)d_in[3];
    const float* bq    = (const float*)d_in[4];
    const float* Wk    = (const float*)d_in[5];
    const float* bk    = (const float*)d_in[6];
    const float* Wv    = (const float*)d_in[7];
    const float* bv    = (const float*)d_in[8];
    const float* Wo    = (const float*)d_in[9];
    const float* bo    = (const float*)d_in[10];
    const float* ln1g  = (const float*)d_in[11];
    const float* ln1b  = (const float*)d_in[12];
    const float* W1    = (const float*)d_in[13];
    const float* b1    = (const float*)d_in[14];
    const float* W2    = (const float*)d_in[15];
    const float* b2    = (const float*)d_in[16];
    const float* ln2g  = (const float*)d_in[17];
    const float* ln2b  = (const float*)d_in[18];
    const float* fw    = (const float*)d_in[19];
    const float* fb    = (const float*)d_in[20];
    float* out = (float*)d_out;

    // workspace layout (floats)
    float* ws = (float*)d_ws;
    const size_t HROWS = (size_t)PRE_ROWS * DM;        // 2,621,440
    float* h   = ws;
    float* qa  = ws + HROWS;
    float* pre = ws + 2 * HROWS;                       // prefill-only
    float* ff  = ws + 3 * HROWS;                       // prefill-only
    float* Kc  = ws + 3 * HROWS + (size_t)PRE_ROWS * DFF;
    float* Vc  = Kc + (size_t)NLAY * BN * TT * DM;
    const size_t LSL = (size_t)BN * TT * DM;
    // f16 KV overlays the dead prefill pre+ff region
    h2_t* K16 = (h2_t*)pre;
    h2_t* V16 = K16 + (size_t)NLAY * BN * TT * 128;
    // packed f16 weights after Vc
    float* pk_base = Vc + (size_t)NLAY * BN * TT * DM;
    h2_t* embp = (h2_t*)pk_base;
    h2_t* qp   = embp + 1024;
    h2_t* kp   = qp + 131072;
    h2_t* vp   = kp + 131072;
    h2_t* op   = vp + 131072;
    h2_t* w1p  = op + 131072;
    h2_t* w2p  = w1p + 524288;
    h2_t* pk_end = w2p + 524288;
    // decode comm buffers
    float* opart  = (float*)pk_end;                    // 64 x 4 x 256
    float* f2part = opart + BN * GROUP * DM;
    unsigned* ctrs = (unsigned*)(f2part + BN * GROUP * DM);

    // pack weights
    pack_k<<<dim3(1, 4),    256, 0, stream>>>(emb_w, embp, DM);
    pack_k<<<dim3(1, 512),  256, 0, stream>>>(Wq, qp, DM);
    pack_k<<<dim3(1, 512),  256, 0, stream>>>(Wk, kp, DM);
    pack_k<<<dim3(1, 512),  256, 0, stream>>>(Wv, vp, DM);
    pack_k<<<dim3(1, 512),  256, 0, stream>>>(Wo, op, DM);
    pack_k<<<dim3(4, 512),  256, 0, stream>>>(W1, w1p, DFF);
    pack_k<<<dim3(1, 2048), 256, 0, stream>>>(W2, w2p, DM);
    init_ctr_k<<<1, 64, 0, stream>>>(ctrs);

    copy_out_k<<<(BN * TT * DIN + 255) / 256, 256, 0, stream>>>(X, out, BN * TT * DIN);
    embed_k<<<PRE_ROWS, 256, 0, stream>>>(X, emb_w, emb_b, h);

    for (int li = 0; li < NLAY; ++li) {
        const float* wq = Wq + (size_t)li * DM * DM;
        const float* wk = Wk + (size_t)li * DM * DM;
        const float* wv = Wv + (size_t)li * DM * DM;
        const float* wo = Wo + (size_t)li * DM * DM;
        const float* w1 = W1 + (size_t)li * DM * DFF;
        const float* w2 = W2 + (size_t)li * DFF * DM;
        gemm_k<<<dim3(4, 160), 256, 0, stream>>>(h, wq, bq + li * DM, nullptr, qa,
                                                 PRE_ROWS, DM, DM, 0, 0);
        gemm_k<<<dim3(4, 160), 256, 0, stream>>>(h, wk, bk + li * DM, nullptr, Kc + li * LSL,
                                                 PRE_ROWS, DM, DM, 0, 1);
        gemm_k<<<dim3(4, 160), 256, 0, stream>>>(h, wv, bv + li * DM, nullptr, Vc + li * LSL,
                                                 PRE_ROWS, DM, DM, 0, 1);
        attn_k<<<dim3(ILEN, BN), 256, 0, stream>>>(qa, Kc + li * LSL, Vc + li * LSL, qa);
        gemm_k<<<dim3(4, 160), 256, 0, stream>>>(qa, wo, bo + li * DM, h, pre,
                                                 PRE_ROWS, DM, DM, 2, 0);
        ln_k<<<PRE_ROWS, 256, 0, stream>>>(pre, ln1g + li * DM, ln1b + li * DM, h);
        gemm_k<<<dim3(16, 160), 256, 0, stream>>>(h, w1, b1 + li * DFF, nullptr, ff,
                                                  PRE_ROWS, DFF, DM, 1, 0);
        gemm_k<<<dim3(4, 160), 256, 0, stream>>>(ff, w2, b2 + li * DM, h, pre,
                                                 PRE_ROWS, DM, DFF, 2, 0);
        ln_k<<<PRE_ROWS, 256, 0, stream>>>(pre, ln2g + li * DM, ln2b + li * DM, h);
    }
    final_k<<<BN, 256, 0, stream>>>(h, fw, fb, out);

    // convert prefill KV to f16 (pre/ff are dead now; K16/V16 overlay them)
    kvconv_k<<<20480, 256, 0, stream>>>(Kc, Vc, K16, V16);

    decode4_k<<<BN * GROUP, 1024, 0, stream>>>(X, emb_w, emb_b, bq, bk, bv, bo,
                                               ln1g, ln1b, b1, b2, ln2g, ln2b, fw, fb,
                                               qp, kp, vp, op, w1p, w2p,
                                               K16, V16, opart, f2part, ctrs,
                                               out);
}